// Round 16
// baseline (38.398 us; speedup 1.0000x reference)
//
#include <hip/hip_runtime.h>
#include <math.h>

#define NBANDS 5
#define T_TILE 4
#define PFUNC_ELEMS (32*128*64*64)
#define LOG2E 1.4426950408889634f

// DPP segmented sum over each aligned 8-lane group (VALU pipe, no DS pipe):
//   0xB1 = quad_perm[1,0,3,2] (xor 1), 0x4E = quad_perm[2,3,0,1] (xor 2),
//   0x141 = row_half_mirror (pairs the two quads of each 8-lane group)
#define DPP_ADD(x, ctrl) \
    ((x) + __int_as_float(__builtin_amdgcn_update_dpp(0, __float_as_int(x), (ctrl), 0xF, 0xF, true)))

__global__ __launch_bounds__(512) void bfp_kernel(
        const float* __restrict__ x,      // (32,5,64,128)
        const float* __restrict__ adj,    // (64,64), values in {0,1}
        const float* __restrict__ amask,  // (32,128,5)
        const float* __restrict__ alpha,  // (32,128,5)
        const float* __restrict__ We,     // (5,64)
        const float* __restrict__ be,     // (5,64)
        const float* __restrict__ Wq,     // (16,64)
        const float* __restrict__ Wk,     // (16,64)
        float* __restrict__ out) {
    // 1024 blocks; XCD-bijective swizzle (1024 % 8 == 0)
    const int bid = blockIdx.x;
    const int blk = (bid & 7) * 128 + (bid >> 3);
    const int bt0 = blk * T_TILE;
    const int b = bt0 >> 7;
    const int t0 = bt0 & 127;
    const int tid = threadIdx.x;

    __shared__ __align__(16) float x_s[T_TILE][NBANDS][64];
    __shared__ float xbar_s[T_TILE][NBANDS], xmax_s[T_TILE][NBANDS], xmin_s[T_TILE][NBANDS];
    __shared__ float w_s[T_TILE][NBANDS], mask_s[T_TILE][NBANDS];
    __shared__ float acw_s[NBANDS], bcw_s[NBANDS];

    // hot-loop mapping: thread -> rows (r, r+32), columns j0..j0+7, t in {2*tp, 2*tp+1}
    const int th = tid & 255;
    const int tp = tid >> 8;         // 0 or 1
    const int r  = th >> 3;          // 0..31
    const int j0 = (th & 7) << 3;    // first of 8 owned columns

    // adjacency chunks for both rows (raw 0/1 floats, multiplicative mask)
    const float4 aA0 = *(const float4*)(adj + r * 64 + j0);
    const float4 aA1 = *(const float4*)(adj + r * 64 + j0 + 4);
    const float4 aB0 = *(const float4*)(adj + (r + 32) * 64 + j0);
    const float4 aB1 = *(const float4*)(adj + (r + 32) * 64 + j0 + 4);

    // issue x staging loads early (waves 0..4)
    float4 xstage;
    if (tid < NBANDS * 64)
        xstage = *(const float4*)(x + ((size_t)b * 320 + tid) * 128 + t0);

    // amask/alpha staging on wave 7 (waves 0-4 run fused prep below)
    if (tid >= 512 - T_TILE * NBANDS) {
        const int idx = tid - (512 - T_TILE * NBANDS);      // 0..19
        const size_t base = ((size_t)b * 128 + t0) * NBANDS;
        const int t = idx / NBANDS, n = idx % NBANDS;
        float mk = amask[base + idx];
        mask_s[t][n] = mk;
        w_s[t][n] = alpha[base + idx] * mk;
    }

    // fused prep: wave w (0..4) computes band w's AC/BC
    {
        const int wvid = tid >> 6;
        const int lane = tid & 63;
        if (wvid < NBANDS) {
            const int n = wvid;
            const int s = lane >> 2;          // d_s index 0..15
            const int d0c = (lane & 3) * 16;  // d-chunk
            float u = 0.f, v = 0.f, w = 0.f;
            #pragma unroll
            for (int dd = 0; dd < 16; ++dd) {
                int d = d0c + dd;
                float we = We[n * 64 + d], bb = be[n * 64 + d];
                float wq = Wq[s * 64 + d], wk = Wk[s * 64 + d];
                u = fmaf(wq, we, u);   // A_s partial
                v = fmaf(wk, we, v);   // C_s partial
                w = fmaf(wq, bb, w);   // B_s partial
            }
            #pragma unroll
            for (int mk = 1; mk <= 2; mk <<= 1) {   // complete quads over d-chunks
                u += __shfl_xor(u, mk);
                v += __shfl_xor(v, mk);
                w += __shfl_xor(w, mk);
            }
            float ac = u * v, bc = w * v;           // A_s*C_s, B_s*C_s
            #pragma unroll
            for (int mk = 4; mk <= 32; mk <<= 1) {  // sum over the 16 s (each once)
                ac += __shfl_xor(ac, mk);
                bc += __shfl_xor(bc, mk);
            }
            if (lane == 0) {
                acw_s[n] = 0.25f * LOG2E * ac;  // 1/sqrt(d_s) * log2e folded
                bcw_s[n] = 0.25f * LOG2E * bc;
            }
        }
    }

    // write staged x to LDS: x_s[t][n][c]
    if (tid < NBANDS * 64) {
        const int n = tid >> 6, c = tid & 63;
        x_s[0][n][c] = xstage.x;
        x_s[1][n][c] = xstage.y;
        x_s[2][n][c] = xstage.z;
        x_s[3][n][c] = xstage.w;
    }
    __syncthreads();

    // per-(t,band) sum/min/max over 64 electrodes; 20 pairs over 8 waves
    {
        const int wv = tid >> 6, lane = tid & 63;
        for (int pair = wv; pair < T_TILE * NBANDS; pair += 8) {
            const int t = pair & 3, n = pair >> 2;
            float v = x_s[t][n][lane];
            float sm = v, mx = v, mn = v;
            #pragma unroll
            for (int mk = 32; mk >= 1; mk >>= 1) {
                sm += __shfl_xor(sm, mk);
                mx = fmaxf(mx, __shfl_xor(mx, mk));
                mn = fminf(mn, __shfl_xor(mn, mk));
            }
            if (lane == 0) {
                xbar_s[t][n] = sm * (1.f / 64.f);
                xmax_s[t][n] = mx;
                xmin_s[t][n] = mn;
            }
        }
    }
    __syncthreads();

    // embeddings_mean for 4 t's (threads 0..255), regular L2-combined stores
    if (tid < T_TILE * 64) {
        const int t = tid >> 6, d = tid & 63;
        float cnt = 0.f, accm = 0.f;
        #pragma unroll
        for (int n = 0; n < NBANDS; ++n) {
            cnt += mask_s[t][n];
            accm += mask_s[t][n] * fmaf(xbar_s[t][n], We[n * 64 + d], be[n * 64 + d]);
        }
        out[PFUNC_ELEMS + (size_t)(bt0 + t) * 64 + d] = accm / fmaxf(cnt, 1.f);
    }

    // hot loop: 2 t's per thread, 2 rows per thread (column ds_reads shared by rows)
    #pragma unroll
    for (int tt = 0; tt < 2; ++tt) {
        const int t = 2 * tp + tt;

        float accA[8], accB[8];
        #pragma unroll
        for (int jj = 0; jj < 8; ++jj) { accA[jj] = 0.f; accB[jj] = 0.f; }

        #pragma unroll
        for (int n = 0; n < NBANDS; ++n) {
            // per-row base-2 logits coefficients
            const float g2a = fmaf(acw_s[n], x_s[t][n][r],      bcw_s[n]);
            const float g2b = fmaf(acw_s[n], x_s[t][n][r + 32], bcw_s[n]);
            // branchless conservative row bounds over ALL j (unmasked exp2 safe)
            const float negma = -fmaxf(g2a * xmax_s[t][n], g2a * xmin_s[t][n]);
            const float negmb = -fmaxf(g2b * xmax_s[t][n], g2b * xmin_s[t][n]);
            // ONE column read serves both rows (the halved-LDS lever)
            const float4 xv0 = ((const float4*)(&x_s[t][n][j0]))[0];
            const float4 xv1 = ((const float4*)(&x_s[t][n][j0]))[1];

            float ea[8], eb[8];
            ea[0] = __builtin_amdgcn_exp2f(fmaf(g2a, xv0.x, negma));
            ea[1] = __builtin_amdgcn_exp2f(fmaf(g2a, xv0.y, negma));
            ea[2] = __builtin_amdgcn_exp2f(fmaf(g2a, xv0.z, negma));
            ea[3] = __builtin_amdgcn_exp2f(fmaf(g2a, xv0.w, negma));
            ea[4] = __builtin_amdgcn_exp2f(fmaf(g2a, xv1.x, negma));
            ea[5] = __builtin_amdgcn_exp2f(fmaf(g2a, xv1.y, negma));
            ea[6] = __builtin_amdgcn_exp2f(fmaf(g2a, xv1.z, negma));
            ea[7] = __builtin_amdgcn_exp2f(fmaf(g2a, xv1.w, negma));
            eb[0] = __builtin_amdgcn_exp2f(fmaf(g2b, xv0.x, negmb));
            eb[1] = __builtin_amdgcn_exp2f(fmaf(g2b, xv0.y, negmb));
            eb[2] = __builtin_amdgcn_exp2f(fmaf(g2b, xv0.z, negmb));
            eb[3] = __builtin_amdgcn_exp2f(fmaf(g2b, xv0.w, negmb));
            eb[4] = __builtin_amdgcn_exp2f(fmaf(g2b, xv1.x, negmb));
            eb[5] = __builtin_amdgcn_exp2f(fmaf(g2b, xv1.y, negmb));
            eb[6] = __builtin_amdgcn_exp2f(fmaf(g2b, xv1.z, negmb));
            eb[7] = __builtin_amdgcn_exp2f(fmaf(g2b, xv1.w, negmb));

            // masked Z per row (mask folded into Z, NOT into acc)
            float za = ea[0] * aA0.x;
            za = fmaf(ea[1], aA0.y, za); za = fmaf(ea[2], aA0.z, za); za = fmaf(ea[3], aA0.w, za);
            float za1 = ea[4] * aA1.x;
            za1 = fmaf(ea[5], aA1.y, za1); za1 = fmaf(ea[6], aA1.z, za1); za1 = fmaf(ea[7], aA1.w, za1);
            float Za = za + za1;
            float zb = eb[0] * aB0.x;
            zb = fmaf(eb[1], aB0.y, zb); zb = fmaf(eb[2], aB0.z, zb); zb = fmaf(eb[3], aB0.w, zb);
            float zb1 = eb[4] * aB1.x;
            zb1 = fmaf(eb[5], aB1.y, zb1); zb1 = fmaf(eb[6], aB1.z, zb1); zb1 = fmaf(eb[7], aB1.w, zb1);
            float Zb = zb + zb1;

            Za = DPP_ADD(Za, 0xB1); Za = DPP_ADD(Za, 0x4E); Za = DPP_ADD(Za, 0x141);
            Zb = DPP_ADD(Zb, 0xB1); Zb = DPP_ADD(Zb, 0x4E); Zb = DPP_ADD(Zb, 0x141);

            const float sca = w_s[t][n] * __builtin_amdgcn_rcpf(fmaxf(Za, 1e-30f));
            const float scb = w_s[t][n] * __builtin_amdgcn_rcpf(fmaxf(Zb, 1e-30f));
            #pragma unroll
            for (int jj = 0; jj < 8; ++jj) {
                accA[jj] = fmaf(ea[jj], sca, accA[jj]);
                accB[jj] = fmaf(eb[jj], scb, accB[jj]);
            }
        }

        // apply adjacency mask once; regular stores (L2 assembles full lines)
        float4* outA = (float4*)(out + ((size_t)(bt0 + t) * 64 + r) * 64 + j0);
        float4* outB = (float4*)(out + ((size_t)(bt0 + t) * 64 + r + 32) * 64 + j0);
        outA[0] = make_float4(accA[0] * aA0.x, accA[1] * aA0.y, accA[2] * aA0.z, accA[3] * aA0.w);
        outA[1] = make_float4(accA[4] * aA1.x, accA[5] * aA1.y, accA[6] * aA1.z, accA[7] * aA1.w);
        outB[0] = make_float4(accB[0] * aB0.x, accB[1] * aB0.y, accB[2] * aB0.z, accB[3] * aB0.w);
        outB[1] = make_float4(accB[4] * aB1.x, accB[5] * aB1.y, accB[6] * aB1.z, accB[7] * aB1.w);
    }
}

extern "C" void kernel_launch(void* const* d_in, const int* in_sizes, int n_in,
                              void* d_out, int out_size, void* d_ws, size_t ws_size,
                              hipStream_t stream) {
    const float* x     = (const float*)d_in[0];
    const float* adj   = (const float*)d_in[1];
    const float* amask = (const float*)d_in[2];
    const float* alpha = (const float*)d_in[3];
    const float* We    = (const float*)d_in[4];
    const float* be    = (const float*)d_in[5];
    const float* Wq    = (const float*)d_in[6];
    const float* Wk    = (const float*)d_in[7];
    float* out = (float*)d_out;

    bfp_kernel<<<1024, 512, 0, stream>>>(x, adj, amask, alpha, We, be, Wq, Wk, out);
}

// Round 17
// 38.282 us; speedup vs baseline: 1.0030x; 1.0030x over previous
//
#include <hip/hip_runtime.h>
#include <math.h>

#define NBANDS 5
#define T_TILE 4
#define PFUNC_ELEMS (32*128*64*64)
#define LOG2E 1.4426950408889634f

// DPP segmented sum over each aligned 8-lane group (VALU pipe, no DS pipe):
//   0xB1 = quad_perm[1,0,3,2] (xor 1), 0x4E = quad_perm[2,3,0,1] (xor 2),
//   0x141 = row_half_mirror (pairs the two quads of each 8-lane group)
#define DPP_ADD(x, ctrl) \
    ((x) + __int_as_float(__builtin_amdgcn_update_dpp(0, __float_as_int(x), (ctrl), 0xF, 0xF, true)))

__global__ __launch_bounds__(512) void bfp_kernel(
        const float* __restrict__ x,      // (32,5,64,128)
        const float* __restrict__ adj,    // (64,64), values in {0,1}
        const float* __restrict__ amask,  // (32,128,5)
        const float* __restrict__ alpha,  // (32,128,5)
        const float* __restrict__ We,     // (5,64)
        const float* __restrict__ be,     // (5,64)
        const float* __restrict__ Wq,     // (16,64)
        const float* __restrict__ Wk,     // (16,64)
        float* __restrict__ out) {
    // 1024 blocks; XCD-bijective swizzle (1024 % 8 == 0)
    const int bid = blockIdx.x;
    const int blk = (bid & 7) * 128 + (bid >> 3);
    const int bt0 = blk * T_TILE;
    const int b = bt0 >> 7;
    const int t0 = bt0 & 127;
    const int tid = threadIdx.x;

    __shared__ __align__(16) float x_s[T_TILE][NBANDS][64];
    __shared__ float xbar_s[T_TILE][NBANDS];
    __shared__ float w_s[T_TILE][NBANDS], mask_s[T_TILE][NBANDS];
    __shared__ float acw_s[NBANDS], bcw_s[NBANDS], bmax_s[NBANDS];

    const int i = tid >> 3;          // output row 0..63
    const int j0 = (tid & 7) << 3;   // first of 8 owned columns

    // adjacency chunk: raw 0/1 floats used as multiplicative mask
    const float4 a0 = *(const float4*)(adj + i * 64 + j0);
    const float4 a1 = *(const float4*)(adj + i * 64 + j0 + 4);

    // issue x staging loads early (waves 0..4; wave wv covers band n = wv)
    float4 xstage;
    if (tid < NBANDS * 64)
        xstage = *(const float4*)(x + ((size_t)b * 320 + tid) * 128 + t0);

    // amask/alpha staging on wave 7 (waves 0-4 run fused prep below)
    if (tid >= 512 - T_TILE * NBANDS) {
        const int idx = tid - (512 - T_TILE * NBANDS);      // 0..19
        const size_t base = ((size_t)b * 128 + t0) * NBANDS;
        const int t = idx / NBANDS, n = idx % NBANDS;
        float mk = amask[base + idx];
        mask_s[t][n] = mk;
        w_s[t][n] = alpha[base + idx] * mk;
    }

    // fused prep: wave w (0..4) computes band w's AC/BC (independent of xstage,
    // hides under the in-flight staging loads)
    {
        const int wvid = tid >> 6;
        const int lane = tid & 63;
        if (wvid < NBANDS) {
            const int n = wvid;
            const int s = lane >> 2;          // d_s index 0..15
            const int d0c = (lane & 3) * 16;  // d-chunk
            float u = 0.f, v = 0.f, w = 0.f;
            #pragma unroll
            for (int dd = 0; dd < 16; ++dd) {
                int d = d0c + dd;
                float we = We[n * 64 + d], bb = be[n * 64 + d];
                float wq = Wq[s * 64 + d], wk = Wk[s * 64 + d];
                u = fmaf(wq, we, u);   // A_s partial
                v = fmaf(wk, we, v);   // C_s partial
                w = fmaf(wq, bb, w);   // B_s partial
            }
            #pragma unroll
            for (int mk = 1; mk <= 2; mk <<= 1) {   // complete quads over d-chunks
                u += __shfl_xor(u, mk);
                v += __shfl_xor(v, mk);
                w += __shfl_xor(w, mk);
            }
            float ac = u * v, bc = w * v;           // A_s*C_s, B_s*C_s
            #pragma unroll
            for (int mk = 4; mk <= 32; mk <<= 1) {  // sum over the 16 s (each once)
                ac += __shfl_xor(ac, mk);
                bc += __shfl_xor(bc, mk);
            }
            if (lane == 0) {
                acw_s[n] = 0.25f * LOG2E * ac;  // 1/sqrt(d_s) * log2e folded
                bcw_s[n] = 0.25f * LOG2E * bc;
            }
        }
    }

    // write staged x to LDS + per-band absmax bound B_n (values already in regs;
    // replaces the whole per-(t,n) xmax/xmin reduce phase)
    if (tid < NBANDS * 64) {
        const int n = tid >> 6, c = tid & 63;
        x_s[0][n][c] = xstage.x;
        x_s[1][n][c] = xstage.y;
        x_s[2][n][c] = xstage.z;
        x_s[3][n][c] = xstage.w;
        float am = fmaxf(fmaxf(fabsf(xstage.x), fabsf(xstage.y)),
                         fmaxf(fabsf(xstage.z), fabsf(xstage.w)));
        #pragma unroll
        for (int mk = 32; mk >= 1; mk >>= 1)
            am = fmaxf(am, __shfl_xor(am, mk));
        if (c == 0) bmax_s[n] = am;   // max|x| over band n's 4x64 tile
    }
    __syncthreads();   // the ONLY barrier before the hot loop

    for (int t = 0; t < T_TILE; ++t) {
        // burst all LDS reads for this t: 10x ds_read_b128 + 5 scalars in flight
        float4 xv0[NBANDS], xv1[NBANDS];
        float gi[NBANDS];
        #pragma unroll
        for (int n = 0; n < NBANDS; ++n) {
            xv0[n] = ((const float4*)(&x_s[t][n][j0]))[0];
            xv1[n] = ((const float4*)(&x_s[t][n][j0]))[1];
            gi[n]  = x_s[t][n][i];
        }

        float acc[8];
        #pragma unroll
        for (int jj = 0; jj < 8; ++jj) acc[jj] = 0.f;

        #pragma unroll
        for (int n = 0; n < NBANDS; ++n) {
            // base-2 logits coefficient (0.25*log2e folded into acw/bcw)
            const float g2 = fmaf(acw_s[n], gi[n], bcw_s[n]);
            // conservative bound: |g2|*B_n >= g2*x_j for all j -> exp2 args <= 0;
            // self-loop keeps Z >= exp2(-2|g2|B), well above f32 underflow for this data
            const float negm = -fabsf(g2) * bmax_s[n];
            float e0 = __builtin_amdgcn_exp2f(fmaf(g2, xv0[n].x, negm));
            float e1 = __builtin_amdgcn_exp2f(fmaf(g2, xv0[n].y, negm));
            float e2 = __builtin_amdgcn_exp2f(fmaf(g2, xv0[n].z, negm));
            float e3 = __builtin_amdgcn_exp2f(fmaf(g2, xv0[n].w, negm));
            float e4 = __builtin_amdgcn_exp2f(fmaf(g2, xv1[n].x, negm));
            float e5 = __builtin_amdgcn_exp2f(fmaf(g2, xv1[n].y, negm));
            float e6 = __builtin_amdgcn_exp2f(fmaf(g2, xv1[n].z, negm));
            float e7 = __builtin_amdgcn_exp2f(fmaf(g2, xv1[n].w, negm));
            // masked Z via two fma chains (mask folded here, NOT into acc)
            float z0 = e0 * a0.x;
            z0 = fmaf(e1, a0.y, z0);
            z0 = fmaf(e2, a0.z, z0);
            z0 = fmaf(e3, a0.w, z0);
            float z1 = e4 * a1.x;
            z1 = fmaf(e5, a1.y, z1);
            z1 = fmaf(e6, a1.z, z1);
            z1 = fmaf(e7, a1.w, z1);
            float Z = z0 + z1;
            Z = DPP_ADD(Z, 0xB1);    // + lane^1
            Z = DPP_ADD(Z, 0x4E);    // + lane^2
            Z = DPP_ADD(Z, 0x141);   // + mirrored quad (8-lane group total)
            const float sc = w_s[t][n] * __builtin_amdgcn_rcpf(fmaxf(Z, 1e-30f));
            // unmasked accumulate; mask applied once at the store
            acc[0] = fmaf(e0, sc, acc[0]);
            acc[1] = fmaf(e1, sc, acc[1]);
            acc[2] = fmaf(e2, sc, acc[2]);
            acc[3] = fmaf(e3, sc, acc[3]);
            acc[4] = fmaf(e4, sc, acc[4]);
            acc[5] = fmaf(e5, sc, acc[5]);
            acc[6] = fmaf(e6, sc, acc[6]);
            acc[7] = fmaf(e7, sc, acc[7]);
        }

        // apply adjacency mask once; plain stores (L2 assembles full lines)
        float4* outp = (float4*)(out + ((size_t)(bt0 + t) * 64 + i) * 64 + j0);
        outp[0] = make_float4(acc[0] * a0.x, acc[1] * a0.y, acc[2] * a0.z, acc[3] * a0.w);
        outp[1] = make_float4(acc[4] * a1.x, acc[5] * a1.y, acc[6] * a1.z, acc[7] * a1.w);
    }

    // post-hot-loop: xbar reduce + embeddings (overlaps the P_func store drain;
    // x_s is read-only since the barrier, so only one sync needed before reads)
    {
        const int wv = tid >> 6, lane = tid & 63;
        for (int pair = wv; pair < T_TILE * NBANDS; pair += 8) {
            const int t = pair & 3, n = pair >> 2;
            float sm = x_s[t][n][lane];
            #pragma unroll
            for (int mk = 32; mk >= 1; mk >>= 1)
                sm += __shfl_xor(sm, mk);
            if (lane == 0) xbar_s[t][n] = sm * (1.f / 64.f);
        }
    }
    __syncthreads();
    if (tid < T_TILE * 64) {
        const int t = tid >> 6, d = tid & 63;
        float cnt = 0.f, accm = 0.f;
        #pragma unroll
        for (int n = 0; n < NBANDS; ++n) {
            cnt += mask_s[t][n];
            accm += mask_s[t][n] * fmaf(xbar_s[t][n], We[n * 64 + d], be[n * 64 + d]);
        }
        out[PFUNC_ELEMS + (size_t)(bt0 + t) * 64 + d] = accm / fmaxf(cnt, 1.f);
    }
}

extern "C" void kernel_launch(void* const* d_in, const int* in_sizes, int n_in,
                              void* d_out, int out_size, void* d_ws, size_t ws_size,
                              hipStream_t stream) {
    const float* x     = (const float*)d_in[0];
    const float* adj   = (const float*)d_in[1];
    const float* amask = (const float*)d_in[2];
    const float* alpha = (const float*)d_in[3];
    const float* We    = (const float*)d_in[4];
    const float* be    = (const float*)d_in[5];
    const float* Wq    = (const float*)d_in[6];
    const float* Wk    = (const float*)d_in[7];
    float* out = (float*)d_out;

    bfp_kernel<<<1024, 512, 0, stream>>>(x, adj, amask, alpha, We, be, Wq, Wk, out);
}

// Round 18
// 34.259 us; speedup vs baseline: 1.1208x; 1.1174x over previous
//
#include <hip/hip_runtime.h>
#include <math.h>

#define NBANDS 5
#define PFUNC_ELEMS (32*128*64*64)
#define LOG2E 1.4426950408889634f

// ws layout (float offsets):
#define WS_XT    0            // 1310720 floats: x_t[bt*320 + n*64 + c]
#define WS_STATS 1310720      // 20480 float4: {xmax, xmin, w=alpha*mask, xbar}
#define WS_MASK  1392640      // 20480 floats: amask
#define WS_COEF  1413120      // acw[n] at +n, bcw[n] at +8+n
#define WS_FLOATS_NEEDED 1413136ull

// DPP segmented sum over each aligned 8-lane group (VALU pipe):
#define DPP_ADD(x, ctrl) \
    ((x) + __int_as_float(__builtin_amdgcn_update_dpp(0, __float_as_int(x), (ctrl), 0xF, 0xF, true)))

// ---------- Kernel A: transpose x + per-(b,t,n) stats + band coefficients ----------
__global__ __launch_bounds__(256) void bfp_prep_kernel(
        const float* __restrict__ x,      // (32,5,64,128)
        const float* __restrict__ amask,  // (32,128,5)
        const float* __restrict__ alpha,  // (32,128,5)
        const float* __restrict__ We, const float* __restrict__ be,
        const float* __restrict__ Wq, const float* __restrict__ Wk,
        float* __restrict__ ws) {
    const int bid = blockIdx.x;          // 0..159
    const int b = bid / NBANDS, n = bid % NBANDS;
    const int tid = threadIdx.x;
    __shared__ float xt[64][129];        // +1 pad: conflict-free column reads

    // load the 64x128 (c,t) tile, coalesced float4 over t
    for (int idx = tid; idx < 64 * 32; idx += 256) {
        const int c = idx >> 5, q = idx & 31;
        float4 v = *(const float4*)(x + (((size_t)b * NBANDS + n) * 64 + c) * 128 + q * 4);
        xt[c][q * 4 + 0] = v.x;
        xt[c][q * 4 + 1] = v.y;
        xt[c][q * 4 + 2] = v.z;
        xt[c][q * 4 + 3] = v.w;
    }
    __syncthreads();

    // transposed store: x_t[(b*128+t)*5+n][c], c contiguous (coalesced per 16-lane t-group)
    for (int idx = tid; idx < 128 * 16; idx += 256) {
        const int t = idx >> 4, cq = idx & 15;
        float4 v = make_float4(xt[cq * 4 + 0][t], xt[cq * 4 + 1][t],
                               xt[cq * 4 + 2][t], xt[cq * 4 + 3][t]);
        *(float4*)(ws + WS_XT + (((size_t)b * 128 + t) * NBANDS + n) * 64 + cq * 4) = v;
    }

    // per-t stats over the 64 electrodes (threads 0..127, one t each)
    if (tid < 128) {
        const int t = tid;
        float mx = xt[0][t], mn = mx, sm = mx;
        #pragma unroll 8
        for (int c = 1; c < 64; ++c) {
            float v = xt[c][t];
            mx = fmaxf(mx, v);
            mn = fminf(mn, v);
            sm += v;
        }
        const size_t sidx = ((size_t)b * 128 + t) * NBANDS + n;
        const float am = amask[sidx];
        ((float4*)(ws + WS_STATS))[sidx] =
            make_float4(mx, mn, alpha[sidx] * am, sm * (1.f / 64.f));
        ws[WS_MASK + sidx] = am;
    }

    // band coefficients AC/BC (only blocks with b==0; lanes 0..15 of wave 0)
    if (b == 0 && tid < 16) {
        const int s = tid;
        float u = 0.f, v = 0.f, w = 0.f;
        for (int d = 0; d < 64; ++d) {
            const float we = We[n * 64 + d], bb = be[n * 64 + d];
            u = fmaf(Wq[s * 64 + d], we, u);   // A_s
            v = fmaf(Wk[s * 64 + d], we, v);   // C_s
            w = fmaf(Wq[s * 64 + d], bb, w);   // B_s
        }
        float ac = u * v, bc = w * v;
        #pragma unroll
        for (int mk = 1; mk <= 8; mk <<= 1) {
            ac += __shfl_xor(ac, mk);
            bc += __shfl_xor(bc, mk);
        }
        if (s == 0) {
            ws[WS_COEF + n]     = 0.25f * LOG2E * ac;   // 1/sqrt(d_s)*log2e folded
            ws[WS_COEF + 8 + n] = 0.25f * LOG2E * bc;
        }
    }
}

// ---------- Kernel B: zero-LDS, zero-barrier main kernel (one bt per block) ----------
__global__ __launch_bounds__(512) void bfp_main_kernel(
        const float* __restrict__ adj,    // (64,64), values in {0,1}
        const float* __restrict__ We, const float* __restrict__ be,
        const float* __restrict__ ws,
        float* __restrict__ out) {
    const int bid = blockIdx.x;
    const int bt = (bid & 7) * 512 + (bid >> 3);   // XCD-bijective (4096 % 8 == 0)
    const int tid = threadIdx.x;
    const int i = tid >> 3;          // output row
    const int j0 = (tid & 7) << 3;   // first of 8 owned columns

    const float* xtp = ws + WS_XT + (size_t)bt * 320;
    const float4* stp = (const float4*)(ws + WS_STATS) + (size_t)bt * NBANDS;

    const float4 a0 = *(const float4*)(adj + i * 64 + j0);
    const float4 a1 = *(const float4*)(adj + i * 64 + j0 + 4);

    // embeddings (threads 0..63) — independent of the hot loop, no sync needed
    if (tid < 64) {
        float cnt = 0.f, accm = 0.f;
        #pragma unroll
        for (int n = 0; n < NBANDS; ++n) {
            const float mk = ws[WS_MASK + (size_t)bt * NBANDS + n];
            cnt += mk;
            accm += mk * fmaf(stp[n].w, We[n * 64 + tid], be[n * 64 + tid]);
        }
        out[PFUNC_ELEMS + (size_t)bt * 64 + tid] = accm / fmaxf(cnt, 1.f);
    }

    float acc[8];
    #pragma unroll
    for (int jj = 0; jj < 8; ++jj) acc[jj] = 0.f;

    #pragma unroll
    for (int n = 0; n < NBANDS; ++n) {
        const float4 st = stp[n];                         // xmax, xmin, w, xbar
        const float gi = xtp[n * 64 + i];
        const float4 xv0 = *(const float4*)(xtp + n * 64 + j0);
        const float4 xv1 = *(const float4*)(xtp + n * 64 + j0 + 4);
        // base-2 logits coefficient (0.25*log2e folded into coefs)
        const float g2 = fmaf(ws[WS_COEF + n], gi, ws[WS_COEF + 8 + n]);
        // branchless conservative row bound over ALL j (unmasked exp2 safe)
        const float negm = -fmaxf(g2 * st.x, g2 * st.y);
        float e0 = __builtin_amdgcn_exp2f(fmaf(g2, xv0.x, negm));
        float e1 = __builtin_amdgcn_exp2f(fmaf(g2, xv0.y, negm));
        float e2 = __builtin_amdgcn_exp2f(fmaf(g2, xv0.z, negm));
        float e3 = __builtin_amdgcn_exp2f(fmaf(g2, xv0.w, negm));
        float e4 = __builtin_amdgcn_exp2f(fmaf(g2, xv1.x, negm));
        float e5 = __builtin_amdgcn_exp2f(fmaf(g2, xv1.y, negm));
        float e6 = __builtin_amdgcn_exp2f(fmaf(g2, xv1.z, negm));
        float e7 = __builtin_amdgcn_exp2f(fmaf(g2, xv1.w, negm));
        // masked Z via two fma chains (mask folded here, NOT into acc)
        float z0 = e0 * a0.x;
        z0 = fmaf(e1, a0.y, z0);
        z0 = fmaf(e2, a0.z, z0);
        z0 = fmaf(e3, a0.w, z0);
        float z1 = e4 * a1.x;
        z1 = fmaf(e5, a1.y, z1);
        z1 = fmaf(e6, a1.z, z1);
        z1 = fmaf(e7, a1.w, z1);
        float Z = z0 + z1;
        Z = DPP_ADD(Z, 0xB1);    // + lane^1
        Z = DPP_ADD(Z, 0x4E);    // + lane^2
        Z = DPP_ADD(Z, 0x141);   // + mirrored quad (8-lane row total)
        const float sc = st.z * __builtin_amdgcn_rcpf(fmaxf(Z, 1e-30f));
        acc[0] = fmaf(e0, sc, acc[0]);
        acc[1] = fmaf(e1, sc, acc[1]);
        acc[2] = fmaf(e2, sc, acc[2]);
        acc[3] = fmaf(e3, sc, acc[3]);
        acc[4] = fmaf(e4, sc, acc[4]);
        acc[5] = fmaf(e5, sc, acc[5]);
        acc[6] = fmaf(e6, sc, acc[6]);
        acc[7] = fmaf(e7, sc, acc[7]);
    }

    float4* outp = (float4*)(out + ((size_t)bt * 64 + i) * 64 + j0);
    outp[0] = make_float4(acc[0] * a0.x, acc[1] * a0.y, acc[2] * a0.z, acc[3] * a0.w);
    outp[1] = make_float4(acc[4] * a1.x, acc[5] * a1.y, acc[6] * a1.z, acc[7] * a1.w);
}

// ---------- Fallback: verified R15 single-kernel path (used if ws is too small) ----------
__global__ __launch_bounds__(512) void bfp_fallback_kernel(
        const float* __restrict__ x, const float* __restrict__ adj,
        const float* __restrict__ amask, const float* __restrict__ alpha,
        const float* __restrict__ We, const float* __restrict__ be,
        const float* __restrict__ Wq, const float* __restrict__ Wk,
        float* __restrict__ out) {
    const int bid = blockIdx.x;
    const int blk = (bid & 7) * 128 + (bid >> 3);
    const int bt0 = blk * 4;
    const int b = bt0 >> 7;
    const int t0 = bt0 & 127;
    const int tid = threadIdx.x;

    __shared__ __align__(16) float x_s[4][NBANDS][64];
    __shared__ float xbar_s[4][NBANDS], xmax_s[4][NBANDS], xmin_s[4][NBANDS];
    __shared__ float w_s[4][NBANDS], mask_s[4][NBANDS];
    __shared__ float acw_s[NBANDS], bcw_s[NBANDS];

    const int i = tid >> 3;
    const int j0 = (tid & 7) << 3;
    const float4 a0 = *(const float4*)(adj + i * 64 + j0);
    const float4 a1 = *(const float4*)(adj + i * 64 + j0 + 4);

    float4 xstage;
    if (tid < NBANDS * 64)
        xstage = *(const float4*)(x + ((size_t)b * 320 + tid) * 128 + t0);
    if (tid >= 512 - 4 * NBANDS) {
        const int idx = tid - (512 - 4 * NBANDS);
        const size_t base = ((size_t)b * 128 + t0) * NBANDS;
        const int t = idx / NBANDS, n = idx % NBANDS;
        float mk = amask[base + idx];
        mask_s[t][n] = mk;
        w_s[t][n] = alpha[base + idx] * mk;
    }
    {
        const int wvid = tid >> 6, lane = tid & 63;
        if (wvid < NBANDS) {
            const int n = wvid, s = lane >> 2, d0c = (lane & 3) * 16;
            float u = 0.f, v = 0.f, w = 0.f;
            #pragma unroll
            for (int dd = 0; dd < 16; ++dd) {
                int d = d0c + dd;
                float we = We[n * 64 + d], bb = be[n * 64 + d];
                u = fmaf(Wq[s * 64 + d], we, u);
                v = fmaf(Wk[s * 64 + d], we, v);
                w = fmaf(Wq[s * 64 + d], bb, w);
            }
            #pragma unroll
            for (int mk = 1; mk <= 2; mk <<= 1) {
                u += __shfl_xor(u, mk); v += __shfl_xor(v, mk); w += __shfl_xor(w, mk);
            }
            float ac = u * v, bc = w * v;
            #pragma unroll
            for (int mk = 4; mk <= 32; mk <<= 1) {
                ac += __shfl_xor(ac, mk); bc += __shfl_xor(bc, mk);
            }
            if (lane == 0) {
                acw_s[n] = 0.25f * LOG2E * ac;
                bcw_s[n] = 0.25f * LOG2E * bc;
            }
        }
    }
    if (tid < NBANDS * 64) {
        const int n = tid >> 6, c = tid & 63;
        x_s[0][n][c] = xstage.x; x_s[1][n][c] = xstage.y;
        x_s[2][n][c] = xstage.z; x_s[3][n][c] = xstage.w;
    }
    __syncthreads();
    {
        const int wv = tid >> 6, lane = tid & 63;
        for (int pair = wv; pair < 4 * NBANDS; pair += 8) {
            const int t = pair & 3, n = pair >> 2;
            float v = x_s[t][n][lane];
            float sm = v, mx = v, mn = v;
            #pragma unroll
            for (int mk = 32; mk >= 1; mk >>= 1) {
                sm += __shfl_xor(sm, mk);
                mx = fmaxf(mx, __shfl_xor(mx, mk));
                mn = fminf(mn, __shfl_xor(mn, mk));
            }
            if (lane == 0) {
                xbar_s[t][n] = sm * (1.f / 64.f);
                xmax_s[t][n] = mx; xmin_s[t][n] = mn;
            }
        }
    }
    __syncthreads();
    if (tid < 4 * 64) {
        const int t = tid >> 6, d = tid & 63;
        float cnt = 0.f, accm = 0.f;
        #pragma unroll
        for (int n = 0; n < NBANDS; ++n) {
            cnt += mask_s[t][n];
            accm += mask_s[t][n] * fmaf(xbar_s[t][n], We[n * 64 + d], be[n * 64 + d]);
        }
        out[PFUNC_ELEMS + (size_t)(bt0 + t) * 64 + d] = accm / fmaxf(cnt, 1.f);
    }
    for (int t = 0; t < 4; ++t) {
        float4 xv0[NBANDS], xv1[NBANDS];
        float gi[NBANDS];
        #pragma unroll
        for (int n = 0; n < NBANDS; ++n) {
            xv0[n] = ((const float4*)(&x_s[t][n][j0]))[0];
            xv1[n] = ((const float4*)(&x_s[t][n][j0]))[1];
            gi[n] = x_s[t][n][i];
        }
        float acc[8];
        #pragma unroll
        for (int jj = 0; jj < 8; ++jj) acc[jj] = 0.f;
        #pragma unroll
        for (int n = 0; n < NBANDS; ++n) {
            const float g2 = fmaf(acw_s[n], gi[n], bcw_s[n]);
            const float negm = -fmaxf(g2 * xmax_s[t][n], g2 * xmin_s[t][n]);
            float e0 = __builtin_amdgcn_exp2f(fmaf(g2, xv0[n].x, negm));
            float e1 = __builtin_amdgcn_exp2f(fmaf(g2, xv0[n].y, negm));
            float e2 = __builtin_amdgcn_exp2f(fmaf(g2, xv0[n].z, negm));
            float e3 = __builtin_amdgcn_exp2f(fmaf(g2, xv0[n].w, negm));
            float e4 = __builtin_amdgcn_exp2f(fmaf(g2, xv1[n].x, negm));
            float e5 = __builtin_amdgcn_exp2f(fmaf(g2, xv1[n].y, negm));
            float e6 = __builtin_amdgcn_exp2f(fmaf(g2, xv1[n].z, negm));
            float e7 = __builtin_amdgcn_exp2f(fmaf(g2, xv1[n].w, negm));
            float z0 = e0 * a0.x;
            z0 = fmaf(e1, a0.y, z0); z0 = fmaf(e2, a0.z, z0); z0 = fmaf(e3, a0.w, z0);
            float z1 = e4 * a1.x;
            z1 = fmaf(e5, a1.y, z1); z1 = fmaf(e6, a1.z, z1); z1 = fmaf(e7, a1.w, z1);
            float Z = z0 + z1;
            Z = DPP_ADD(Z, 0xB1); Z = DPP_ADD(Z, 0x4E); Z = DPP_ADD(Z, 0x141);
            const float sc = w_s[t][n] * __builtin_amdgcn_rcpf(fmaxf(Z, 1e-30f));
            acc[0] = fmaf(e0, sc, acc[0]); acc[1] = fmaf(e1, sc, acc[1]);
            acc[2] = fmaf(e2, sc, acc[2]); acc[3] = fmaf(e3, sc, acc[3]);
            acc[4] = fmaf(e4, sc, acc[4]); acc[5] = fmaf(e5, sc, acc[5]);
            acc[6] = fmaf(e6, sc, acc[6]); acc[7] = fmaf(e7, sc, acc[7]);
        }
        float4* outp = (float4*)(out + ((size_t)(bt0 + t) * 64 + i) * 64 + j0);
        outp[0] = make_float4(acc[0] * a0.x, acc[1] * a0.y, acc[2] * a0.z, acc[3] * a0.w);
        outp[1] = make_float4(acc[4] * a1.x, acc[5] * a1.y, acc[6] * a1.z, acc[7] * a1.w);
    }
}

extern "C" void kernel_launch(void* const* d_in, const int* in_sizes, int n_in,
                              void* d_out, int out_size, void* d_ws, size_t ws_size,
                              hipStream_t stream) {
    const float* x     = (const float*)d_in[0];
    const float* adj   = (const float*)d_in[1];
    const float* amask = (const float*)d_in[2];
    const float* alpha = (const float*)d_in[3];
    const float* We    = (const float*)d_in[4];
    const float* be    = (const float*)d_in[5];
    const float* Wq    = (const float*)d_in[6];
    const float* Wk    = (const float*)d_in[7];
    float* ws  = (float*)d_ws;
    float* out = (float*)d_out;

    if (ws_size >= WS_FLOATS_NEEDED * sizeof(float)) {
        bfp_prep_kernel<<<160, 256, 0, stream>>>(x, amask, alpha, We, be, Wq, Wk, ws);
        bfp_main_kernel<<<4096, 512, 0, stream>>>(adj, We, be, ws, out);
    } else {
        bfp_fallback_kernel<<<1024, 512, 0, stream>>>(x, adj, amask, alpha, We, be, Wq, Wk, out);
    }
}

// Round 19
// 31.465 us; speedup vs baseline: 1.2204x; 1.0888x over previous
//
#include <hip/hip_runtime.h>
#include <math.h>

#define NBANDS 5
#define T_TILE 4
#define PFUNC_ELEMS (32*128*64*64)
#define LOG2E 1.4426950408889634f

// DPP segmented sum over each aligned 8-lane group (VALU pipe, no DS pipe):
//   0xB1 = quad_perm[1,0,3,2] (xor 1), 0x4E = quad_perm[2,3,0,1] (xor 2),
//   0x141 = row_half_mirror (pairs the two quads of each 8-lane group)
#define DPP_ADD(x, ctrl) \
    ((x) + __int_as_float(__builtin_amdgcn_update_dpp(0, __float_as_int(x), (ctrl), 0xF, 0xF, true)))

__global__ __launch_bounds__(512) void bfp_kernel(
        const float* __restrict__ x,      // (32,5,64,128)
        const float* __restrict__ adj,    // (64,64), values in {0,1}
        const float* __restrict__ amask,  // (32,128,5)
        const float* __restrict__ alpha,  // (32,128,5)
        const float* __restrict__ We,     // (5,64)
        const float* __restrict__ be,     // (5,64)
        const float* __restrict__ Wq,     // (16,64)
        const float* __restrict__ Wk,     // (16,64)
        float* __restrict__ out) {
    // 1024 blocks; XCD-bijective swizzle (1024 % 8 == 0)
    const int bid = blockIdx.x;
    const int blk = (bid & 7) * 128 + (bid >> 3);
    const int bt0 = blk * T_TILE;
    const int b = bt0 >> 7;
    const int t0 = bt0 & 127;
    const int tid = threadIdx.x;

    __shared__ __align__(16) float x_s[T_TILE][NBANDS][64];
    __shared__ float xbar_s[T_TILE][NBANDS], xmax_s[T_TILE][NBANDS], xmin_s[T_TILE][NBANDS];
    __shared__ float w_s[T_TILE][NBANDS], mask_s[T_TILE][NBANDS];
    __shared__ float acw_s[NBANDS], bcw_s[NBANDS];

    const int i = tid >> 3;          // output row 0..63
    const int j0 = (tid & 7) << 3;   // first of 8 owned columns

    // adjacency chunk: raw 0/1 floats used as multiplicative mask
    const float4 a0 = *(const float4*)(adj + i * 64 + j0);
    const float4 a1 = *(const float4*)(adj + i * 64 + j0 + 4);

    // issue x staging loads early (waves 0..4)
    float4 xstage;
    if (tid < NBANDS * 64)
        xstage = *(const float4*)(x + ((size_t)b * 320 + tid) * 128 + t0);

    // amask/alpha staging on wave 7 (waves 0-4 run fused prep below)
    if (tid >= 512 - T_TILE * NBANDS) {
        const int idx = tid - (512 - T_TILE * NBANDS);      // 0..19
        const size_t base = ((size_t)b * 128 + t0) * NBANDS;
        const int t = idx / NBANDS, n = idx % NBANDS;
        float mk = amask[base + idx];
        mask_s[t][n] = mk;
        w_s[t][n] = alpha[base + idx] * mk;
    }

    // fused prep: wave w (0..4) computes band w's AC/BC
    {
        const int wvid = tid >> 6;
        const int lane = tid & 63;
        if (wvid < NBANDS) {
            const int n = wvid;
            const int s = lane >> 2;          // d_s index 0..15
            const int d0c = (lane & 3) * 16;  // d-chunk
            float u = 0.f, v = 0.f, w = 0.f;
            #pragma unroll
            for (int dd = 0; dd < 16; ++dd) {
                int d = d0c + dd;
                float we = We[n * 64 + d], bb = be[n * 64 + d];
                float wq = Wq[s * 64 + d], wk = Wk[s * 64 + d];
                u = fmaf(wq, we, u);   // A_s partial
                v = fmaf(wk, we, v);   // C_s partial
                w = fmaf(wq, bb, w);   // B_s partial
            }
            #pragma unroll
            for (int mk = 1; mk <= 2; mk <<= 1) {   // complete quads over d-chunks
                u += __shfl_xor(u, mk);
                v += __shfl_xor(v, mk);
                w += __shfl_xor(w, mk);
            }
            float ac = u * v, bc = w * v;           // A_s*C_s, B_s*C_s
            #pragma unroll
            for (int mk = 4; mk <= 32; mk <<= 1) {  // sum over the 16 s (each once)
                ac += __shfl_xor(ac, mk);
                bc += __shfl_xor(bc, mk);
            }
            if (lane == 0) {
                acw_s[n] = 0.25f * LOG2E * ac;  // 1/sqrt(d_s) * log2e folded
                bcw_s[n] = 0.25f * LOG2E * bc;
            }
        }
    }

    // write staged x to LDS: x_s[t][n][c]
    if (tid < NBANDS * 64) {
        const int n = tid >> 6, c = tid & 63;
        x_s[0][n][c] = xstage.x;
        x_s[1][n][c] = xstage.y;
        x_s[2][n][c] = xstage.z;
        x_s[3][n][c] = xstage.w;
    }
    __syncthreads();

    // per-(t,band) sum/min/max over 64 electrodes; 20 pairs over 8 waves
    {
        const int wv = tid >> 6, lane = tid & 63;
        for (int pair = wv; pair < T_TILE * NBANDS; pair += 8) {
            const int t = pair & 3, n = pair >> 2;
            float v = x_s[t][n][lane];
            float sm = v, mx = v, mn = v;
            #pragma unroll
            for (int mk = 32; mk >= 1; mk >>= 1) {
                sm += __shfl_xor(sm, mk);
                mx = fmaxf(mx, __shfl_xor(mx, mk));
                mn = fminf(mn, __shfl_xor(mn, mk));
            }
            if (lane == 0) {
                xbar_s[t][n] = sm * (1.f / 64.f);
                xmax_s[t][n] = mx;
                xmin_s[t][n] = mn;
            }
        }
    }
    __syncthreads();

    // embeddings_mean for 4 t's (threads 0..255)
    if (tid < T_TILE * 64) {
        const int t = tid >> 6, d = tid & 63;
        float cnt = 0.f, accm = 0.f;
        #pragma unroll
        for (int n = 0; n < NBANDS; ++n) {
            cnt += mask_s[t][n];
            accm += mask_s[t][n] * fmaf(xbar_s[t][n], We[n * 64 + d], be[n * 64 + d]);
        }
        out[PFUNC_ELEMS + (size_t)(bt0 + t) * 64 + d] = accm / fmaxf(cnt, 1.f);
    }

    // hot loop: two-band software pipeline — band n+1's exp2s (trans pipe)
    // overlap band n's Z/DPP/acc (VALU pipe) instead of ping-ponging.
    for (int t = 0; t < T_TILE; ++t) {
        float acc[8];
        #pragma unroll
        for (int jj = 0; jj < 8; ++jj) acc[jj] = 0.f;

        // prologue: band 0's exps
        float eC0, eC1, eC2, eC3, eC4, eC5, eC6, eC7;
        {
            const float g2 = fmaf(acw_s[0], x_s[t][0][i], bcw_s[0]);
            const float negm = -fmaxf(g2 * xmax_s[t][0], g2 * xmin_s[t][0]);
            const float4 xv0 = ((const float4*)(&x_s[t][0][j0]))[0];
            const float4 xv1 = ((const float4*)(&x_s[t][0][j0]))[1];
            eC0 = __builtin_amdgcn_exp2f(fmaf(g2, xv0.x, negm));
            eC1 = __builtin_amdgcn_exp2f(fmaf(g2, xv0.y, negm));
            eC2 = __builtin_amdgcn_exp2f(fmaf(g2, xv0.z, negm));
            eC3 = __builtin_amdgcn_exp2f(fmaf(g2, xv0.w, negm));
            eC4 = __builtin_amdgcn_exp2f(fmaf(g2, xv1.x, negm));
            eC5 = __builtin_amdgcn_exp2f(fmaf(g2, xv1.y, negm));
            eC6 = __builtin_amdgcn_exp2f(fmaf(g2, xv1.z, negm));
            eC7 = __builtin_amdgcn_exp2f(fmaf(g2, xv1.w, negm));
        }

        #pragma unroll
        for (int n = 0; n < NBANDS; ++n) {
            // issue band n+1's exp2s FIRST (trans pipe fills while VALU consumes band n)
            float eN0, eN1, eN2, eN3, eN4, eN5, eN6, eN7;
            if (n < NBANDS - 1) {
                const int m = n + 1;
                const float g2 = fmaf(acw_s[m], x_s[t][m][i], bcw_s[m]);
                const float negm = -fmaxf(g2 * xmax_s[t][m], g2 * xmin_s[t][m]);
                const float4 xv0 = ((const float4*)(&x_s[t][m][j0]))[0];
                const float4 xv1 = ((const float4*)(&x_s[t][m][j0]))[1];
                eN0 = __builtin_amdgcn_exp2f(fmaf(g2, xv0.x, negm));
                eN1 = __builtin_amdgcn_exp2f(fmaf(g2, xv0.y, negm));
                eN2 = __builtin_amdgcn_exp2f(fmaf(g2, xv0.z, negm));
                eN3 = __builtin_amdgcn_exp2f(fmaf(g2, xv0.w, negm));
                eN4 = __builtin_amdgcn_exp2f(fmaf(g2, xv1.x, negm));
                eN5 = __builtin_amdgcn_exp2f(fmaf(g2, xv1.y, negm));
                eN6 = __builtin_amdgcn_exp2f(fmaf(g2, xv1.z, negm));
                eN7 = __builtin_amdgcn_exp2f(fmaf(g2, xv1.w, negm));
            }

            // consume band n on the VALU pipe (masked Z, DPP reduce, acc)
            float z0 = eC0 * a0.x;
            z0 = fmaf(eC1, a0.y, z0);
            z0 = fmaf(eC2, a0.z, z0);
            z0 = fmaf(eC3, a0.w, z0);
            float z1 = eC4 * a1.x;
            z1 = fmaf(eC5, a1.y, z1);
            z1 = fmaf(eC6, a1.z, z1);
            z1 = fmaf(eC7, a1.w, z1);
            float Z = z0 + z1;
            Z = DPP_ADD(Z, 0xB1);    // + lane^1
            Z = DPP_ADD(Z, 0x4E);    // + lane^2
            Z = DPP_ADD(Z, 0x141);   // + mirrored quad (8-lane group total)
            const float sc = w_s[t][n] * __builtin_amdgcn_rcpf(fmaxf(Z, 1e-30f));
            acc[0] = fmaf(eC0, sc, acc[0]);
            acc[1] = fmaf(eC1, sc, acc[1]);
            acc[2] = fmaf(eC2, sc, acc[2]);
            acc[3] = fmaf(eC3, sc, acc[3]);
            acc[4] = fmaf(eC4, sc, acc[4]);
            acc[5] = fmaf(eC5, sc, acc[5]);
            acc[6] = fmaf(eC6, sc, acc[6]);
            acc[7] = fmaf(eC7, sc, acc[7]);

            // compile-time register rename (fully unrolled)
            if (n < NBANDS - 1) {
                eC0 = eN0; eC1 = eN1; eC2 = eN2; eC3 = eN3;
                eC4 = eN4; eC5 = eN5; eC6 = eN6; eC7 = eN7;
            }
        }

        // apply adjacency mask once; plain stores (L2 assembles full lines)
        float4* outp = (float4*)(out + ((size_t)(bt0 + t) * 64 + i) * 64 + j0);
        outp[0] = make_float4(acc[0] * a0.x, acc[1] * a0.y, acc[2] * a0.z, acc[3] * a0.w);
        outp[1] = make_float4(acc[4] * a1.x, acc[5] * a1.y, acc[6] * a1.z, acc[7] * a1.w);
    }
}

extern "C" void kernel_launch(void* const* d_in, const int* in_sizes, int n_in,
                              void* d_out, int out_size, void* d_ws, size_t ws_size,
                              hipStream_t stream) {
    const float* x     = (const float*)d_in[0];
    const float* adj   = (const float*)d_in[1];
    const float* amask = (const float*)d_in[2];
    const float* alpha = (const float*)d_in[3];
    const float* We    = (const float*)d_in[4];
    const float* be    = (const float*)d_in[5];
    const float* Wq    = (const float*)d_in[6];
    const float* Wk    = (const float*)d_in[7];
    float* out = (float*)d_out;

    bfp_kernel<<<1024, 512, 0, stream>>>(x, adj, amask, alpha, We, be, Wq, Wk, out);
}

// Round 20
// 29.130 us; speedup vs baseline: 1.3182x; 1.0802x over previous
//
#include <hip/hip_runtime.h>
#include <math.h>

#define NBANDS 5
#define T_TILE 4
#define PFUNC_ELEMS (32*128*64*64)
#define LOG2E 1.4426950408889634f

typedef __attribute__((ext_vector_type(4))) float f32x4;

// DPP segmented sum over each aligned 8-lane group (VALU pipe, no DS pipe):
//   0xB1 = quad_perm[1,0,3,2] (xor 1), 0x4E = quad_perm[2,3,0,1] (xor 2),
//   0x141 = row_half_mirror (pairs the two quads of each 8-lane group)
#define DPP_ADD(x, ctrl) \
    ((x) + __int_as_float(__builtin_amdgcn_update_dpp(0, __float_as_int(x), (ctrl), 0xF, 0xF, true)))

__global__ __launch_bounds__(512) void bfp_kernel(
        const float* __restrict__ x,      // (32,5,64,128)
        const float* __restrict__ adj,    // (64,64), values in {0,1}
        const float* __restrict__ amask,  // (32,128,5)
        const float* __restrict__ alpha,  // (32,128,5)
        const float* __restrict__ We,     // (5,64)
        const float* __restrict__ be,     // (5,64)
        const float* __restrict__ Wq,     // (16,64)
        const float* __restrict__ Wk,     // (16,64)
        float* __restrict__ out) {
    // 1024 blocks; XCD-bijective swizzle (1024 % 8 == 0)
    const int bid = blockIdx.x;
    const int blk = (bid & 7) * 128 + (bid >> 3);
    const int bt0 = blk * T_TILE;
    const int b = bt0 >> 7;
    const int t0 = bt0 & 127;
    const int tid = threadIdx.x;

    __shared__ __align__(16) float x_s[T_TILE][NBANDS][64];
    __shared__ float xbar_s[T_TILE][NBANDS], xmax_s[T_TILE][NBANDS], xmin_s[T_TILE][NBANDS];
    __shared__ float w_s[T_TILE][NBANDS], mask_s[T_TILE][NBANDS];
    __shared__ float acw_s[NBANDS], bcw_s[NBANDS];

    const int i = tid >> 3;          // output row 0..63
    // CONTIGUOUS-STORE column mapping: thread q=(tid&7) owns cols
    // {4q..4q+3} and {32+4q..32+4q+3}. Each store instruction's 8-lane
    // group then covers a contiguous 128 B span -> full 64 B lines for nt.
    const int jA = (tid & 7) << 2;   // first quad
    const int jB = jA + 32;          // second quad

    // adjacency quads for both column groups (raw 0/1 multiplicative mask)
    const float4 a0 = *(const float4*)(adj + i * 64 + jA);
    const float4 a1 = *(const float4*)(adj + i * 64 + jB);

    // issue x staging loads early (waves 0..4)
    float4 xstage;
    if (tid < NBANDS * 64)
        xstage = *(const float4*)(x + ((size_t)b * 320 + tid) * 128 + t0);

    // amask/alpha staging on wave 7 (waves 0-4 run fused prep below)
    if (tid >= 512 - T_TILE * NBANDS) {
        const int idx = tid - (512 - T_TILE * NBANDS);      // 0..19
        const size_t base = ((size_t)b * 128 + t0) * NBANDS;
        const int t = idx / NBANDS, n = idx % NBANDS;
        float mk = amask[base + idx];
        mask_s[t][n] = mk;
        w_s[t][n] = alpha[base + idx] * mk;
    }

    // fused prep: wave w (0..4) computes band w's AC/BC
    {
        const int wvid = tid >> 6;
        const int lane = tid & 63;
        if (wvid < NBANDS) {
            const int n = wvid;
            const int s = lane >> 2;          // d_s index 0..15
            const int d0c = (lane & 3) * 16;  // d-chunk
            float u = 0.f, v = 0.f, w = 0.f;
            #pragma unroll
            for (int dd = 0; dd < 16; ++dd) {
                int d = d0c + dd;
                float we = We[n * 64 + d], bb = be[n * 64 + d];
                float wq = Wq[s * 64 + d], wk = Wk[s * 64 + d];
                u = fmaf(wq, we, u);   // A_s partial
                v = fmaf(wk, we, v);   // C_s partial
                w = fmaf(wq, bb, w);   // B_s partial
            }
            #pragma unroll
            for (int mk = 1; mk <= 2; mk <<= 1) {   // complete quads over d-chunks
                u += __shfl_xor(u, mk);
                v += __shfl_xor(v, mk);
                w += __shfl_xor(w, mk);
            }
            float ac = u * v, bc = w * v;           // A_s*C_s, B_s*C_s
            #pragma unroll
            for (int mk = 4; mk <= 32; mk <<= 1) {  // sum over the 16 s (each once)
                ac += __shfl_xor(ac, mk);
                bc += __shfl_xor(bc, mk);
            }
            if (lane == 0) {
                acw_s[n] = 0.25f * LOG2E * ac;  // 1/sqrt(d_s) * log2e folded
                bcw_s[n] = 0.25f * LOG2E * bc;
            }
        }
    }

    // write staged x to LDS: x_s[t][n][c]
    if (tid < NBANDS * 64) {
        const int n = tid >> 6, c = tid & 63;
        x_s[0][n][c] = xstage.x;
        x_s[1][n][c] = xstage.y;
        x_s[2][n][c] = xstage.z;
        x_s[3][n][c] = xstage.w;
    }
    __syncthreads();

    // per-(t,band) sum/min/max over 64 electrodes; 20 pairs over 8 waves
    {
        const int wv = tid >> 6, lane = tid & 63;
        for (int pair = wv; pair < T_TILE * NBANDS; pair += 8) {
            const int t = pair & 3, n = pair >> 2;
            float v = x_s[t][n][lane];
            float sm = v, mx = v, mn = v;
            #pragma unroll
            for (int mk = 32; mk >= 1; mk >>= 1) {
                sm += __shfl_xor(sm, mk);
                mx = fmaxf(mx, __shfl_xor(mx, mk));
                mn = fminf(mn, __shfl_xor(mn, mk));
            }
            if (lane == 0) {
                xbar_s[t][n] = sm * (1.f / 64.f);
                xmax_s[t][n] = mx;
                xmin_s[t][n] = mn;
            }
        }
    }
    __syncthreads();

    // embeddings_mean for 4 t's (threads 0..255), regular L2-combined stores
    if (tid < T_TILE * 64) {
        const int t = tid >> 6, d = tid & 63;
        float cnt = 0.f, accm = 0.f;
        #pragma unroll
        for (int n = 0; n < NBANDS; ++n) {
            cnt += mask_s[t][n];
            accm += mask_s[t][n] * fmaf(xbar_s[t][n], We[n * 64 + d], be[n * 64 + d]);
        }
        out[PFUNC_ELEMS + (size_t)(bt0 + t) * 64 + d] = accm / fmaxf(cnt, 1.f);
    }

    for (int t = 0; t < T_TILE; ++t) {
        // burst all LDS reads for this t: 10x ds_read_b128 + 5 scalars in flight
        float4 xv0[NBANDS], xv1[NBANDS];
        float gi[NBANDS];
        #pragma unroll
        for (int n = 0; n < NBANDS; ++n) {
            xv0[n] = *(const float4*)(&x_s[t][n][jA]);
            xv1[n] = *(const float4*)(&x_s[t][n][jB]);
            gi[n]  = x_s[t][n][i];
        }

        float acc[8];
        #pragma unroll
        for (int jj = 0; jj < 8; ++jj) acc[jj] = 0.f;

        #pragma unroll
        for (int n = 0; n < NBANDS; ++n) {
            // base-2 logits coefficient (0.25*log2e folded into acw/bcw)
            const float g2 = fmaf(acw_s[n], gi[n], bcw_s[n]);
            // branchless conservative row bound over ALL j (unmasked exp2 safe)
            const float negm = -fmaxf(g2 * xmax_s[t][n], g2 * xmin_s[t][n]);
            float e0 = __builtin_amdgcn_exp2f(fmaf(g2, xv0[n].x, negm));
            float e1 = __builtin_amdgcn_exp2f(fmaf(g2, xv0[n].y, negm));
            float e2 = __builtin_amdgcn_exp2f(fmaf(g2, xv0[n].z, negm));
            float e3 = __builtin_amdgcn_exp2f(fmaf(g2, xv0[n].w, negm));
            float e4 = __builtin_amdgcn_exp2f(fmaf(g2, xv1[n].x, negm));
            float e5 = __builtin_amdgcn_exp2f(fmaf(g2, xv1[n].y, negm));
            float e6 = __builtin_amdgcn_exp2f(fmaf(g2, xv1[n].z, negm));
            float e7 = __builtin_amdgcn_exp2f(fmaf(g2, xv1[n].w, negm));
            // masked Z via two fma chains (mask folded here, NOT into acc);
            // lanes of the 8-lane group jointly cover all 64 cols, so the
            // DPP reduce below still yields the full row sum.
            float z0 = e0 * a0.x;
            z0 = fmaf(e1, a0.y, z0);
            z0 = fmaf(e2, a0.z, z0);
            z0 = fmaf(e3, a0.w, z0);
            float z1 = e4 * a1.x;
            z1 = fmaf(e5, a1.y, z1);
            z1 = fmaf(e6, a1.z, z1);
            z1 = fmaf(e7, a1.w, z1);
            float Z = z0 + z1;
            Z = DPP_ADD(Z, 0xB1);    // + lane^1
            Z = DPP_ADD(Z, 0x4E);    // + lane^2
            Z = DPP_ADD(Z, 0x141);   // + mirrored quad (8-lane group total)
            const float sc = w_s[t][n] * __builtin_amdgcn_rcpf(fmaxf(Z, 1e-30f));
            // unmasked accumulate; mask applied once at the store
            acc[0] = fmaf(e0, sc, acc[0]);
            acc[1] = fmaf(e1, sc, acc[1]);
            acc[2] = fmaf(e2, sc, acc[2]);
            acc[3] = fmaf(e3, sc, acc[3]);
            acc[4] = fmaf(e4, sc, acc[4]);
            acc[5] = fmaf(e5, sc, acc[5]);
            acc[6] = fmaf(e6, sc, acc[6]);
            acc[7] = fmaf(e7, sc, acc[7]);
        }

        // apply adjacency mask once; nt stores now form FULL 64 B lines
        // (each instruction's 8-lane group = contiguous 128 B span)
        float* rowp = out + ((size_t)(bt0 + t) * 64 + i) * 64;
        f32x4 o0 = {acc[0] * a0.x, acc[1] * a0.y, acc[2] * a0.z, acc[3] * a0.w};
        f32x4 o1 = {acc[4] * a1.x, acc[5] * a1.y, acc[6] * a1.z, acc[7] * a1.w};
        __builtin_nontemporal_store(o0, (f32x4*)(rowp + jA));
        __builtin_nontemporal_store(o1, (f32x4*)(rowp + jB));
    }
}

extern "C" void kernel_launch(void* const* d_in, const int* in_sizes, int n_in,
                              void* d_out, int out_size, void* d_ws, size_t ws_size,
                              hipStream_t stream) {
    const float* x     = (const float*)d_in[0];
    const float* adj   = (const float*)d_in[1];
    const float* amask = (const float*)d_in[2];
    const float* alpha = (const float*)d_in[3];
    const float* We    = (const float*)d_in[4];
    const float* be    = (const float*)d_in[5];
    const float* Wq    = (const float*)d_in[6];
    const float* Wk    = (const float*)d_in[7];
    float* out = (float*)d_out;

    bfp_kernel<<<1024, 512, 0, stream>>>(x, adj, amask, alpha, We, be, Wq, Wk, out);
}

// Round 21
// 28.290 us; speedup vs baseline: 1.3573x; 1.0297x over previous
//
#include <hip/hip_runtime.h>
#include <math.h>

#define NBANDS 5
#define T_TILE 8
#define PFUNC_ELEMS (32*128*64*64)
#define LOG2E 1.4426950408889634f

typedef __attribute__((ext_vector_type(4))) float f32x4;

// DPP segmented sum over each aligned 8-lane group (VALU pipe, no DS pipe):
//   0xB1 = quad_perm[1,0,3,2] (xor 1), 0x4E = quad_perm[2,3,0,1] (xor 2),
//   0x141 = row_half_mirror (pairs the two quads of each 8-lane group)
#define DPP_ADD(x, ctrl) \
    ((x) + __int_as_float(__builtin_amdgcn_update_dpp(0, __float_as_int(x), (ctrl), 0xF, 0xF, true)))

__global__ __launch_bounds__(512) void bfp_kernel(
        const float* __restrict__ x,      // (32,5,64,128)
        const float* __restrict__ adj,    // (64,64), values in {0,1}
        const float* __restrict__ amask,  // (32,128,5)
        const float* __restrict__ alpha,  // (32,128,5)
        const float* __restrict__ We,     // (5,64)
        const float* __restrict__ be,     // (5,64)
        const float* __restrict__ Wq,     // (16,64)
        const float* __restrict__ Wk,     // (16,64)
        float* __restrict__ out) {
    // 512 blocks; XCD-bijective swizzle (512 % 8 == 0)
    const int bid = blockIdx.x;
    const int blk = (bid & 7) * 64 + (bid >> 3);
    const int bt0 = blk * T_TILE;
    const int b = bt0 >> 7;
    const int t0 = bt0 & 127;        // multiple of 8
    const int tid = threadIdx.x;

    __shared__ __align__(16) float x_s[T_TILE][NBANDS][64];
    __shared__ float xbar_s[T_TILE][NBANDS], xmax_s[T_TILE][NBANDS], xmin_s[T_TILE][NBANDS];
    __shared__ float w_s[T_TILE][NBANDS], mask_s[T_TILE][NBANDS];
    __shared__ float acw_s[NBANDS], bcw_s[NBANDS];

    const int i = tid >> 3;          // output row 0..63
    // contiguous-store column mapping (R20): thread q=(tid&7) owns cols
    // {4q..4q+3} and {32+4q..32+4q+3}; each store's 8-lane group = 128 B span.
    const int jA = (tid & 7) << 2;
    const int jB = jA + 32;

    // adjacency quads for both column groups (raw 0/1 multiplicative mask)
    const float4 a0 = *(const float4*)(adj + i * 64 + jA);
    const float4 a1 = *(const float4*)(adj + i * 64 + jB);

    // issue x staging loads early (waves 0..4): t0..t0+7 as two float4s
    float4 xs0, xs1;
    if (tid < NBANDS * 64) {
        const float* xp = x + ((size_t)b * 320 + tid) * 128 + t0;
        xs0 = *(const float4*)(xp);
        xs1 = *(const float4*)(xp + 4);
    }

    // amask/alpha staging on wave 7 (waves 0-4 run fused prep below)
    if (tid >= 512 - T_TILE * NBANDS) {
        const int idx = tid - (512 - T_TILE * NBANDS);      // 0..39
        const size_t base = ((size_t)b * 128 + t0) * NBANDS;
        const int t = idx / NBANDS, n = idx % NBANDS;
        float mk = amask[base + idx];
        mask_s[t][n] = mk;
        w_s[t][n] = alpha[base + idx] * mk;
    }

    // fused prep: wave w (0..4) computes band w's AC/BC
    {
        const int wvid = tid >> 6;
        const int lane = tid & 63;
        if (wvid < NBANDS) {
            const int n = wvid;
            const int s = lane >> 2;          // d_s index 0..15
            const int d0c = (lane & 3) * 16;  // d-chunk
            float u = 0.f, v = 0.f, w = 0.f;
            #pragma unroll
            for (int dd = 0; dd < 16; ++dd) {
                int d = d0c + dd;
                float we = We[n * 64 + d], bb = be[n * 64 + d];
                float wq = Wq[s * 64 + d], wk = Wk[s * 64 + d];
                u = fmaf(wq, we, u);   // A_s partial
                v = fmaf(wk, we, v);   // C_s partial
                w = fmaf(wq, bb, w);   // B_s partial
            }
            #pragma unroll
            for (int mk = 1; mk <= 2; mk <<= 1) {   // complete quads over d-chunks
                u += __shfl_xor(u, mk);
                v += __shfl_xor(v, mk);
                w += __shfl_xor(w, mk);
            }
            float ac = u * v, bc = w * v;           // A_s*C_s, B_s*C_s
            #pragma unroll
            for (int mk = 4; mk <= 32; mk <<= 1) {  // sum over the 16 s (each once)
                ac += __shfl_xor(ac, mk);
                bc += __shfl_xor(bc, mk);
            }
            if (lane == 0) {
                acw_s[n] = 0.25f * LOG2E * ac;  // 1/sqrt(d_s) * log2e folded
                bcw_s[n] = 0.25f * LOG2E * bc;
            }
        }
    }

    // write staged x to LDS: x_s[t][n][c]
    if (tid < NBANDS * 64) {
        const int n = tid >> 6, c = tid & 63;
        x_s[0][n][c] = xs0.x;
        x_s[1][n][c] = xs0.y;
        x_s[2][n][c] = xs0.z;
        x_s[3][n][c] = xs0.w;
        x_s[4][n][c] = xs1.x;
        x_s[5][n][c] = xs1.y;
        x_s[6][n][c] = xs1.z;
        x_s[7][n][c] = xs1.w;
    }
    __syncthreads();

    // per-(t,band) sum/min/max over 64 electrodes; 40 pairs over 8 waves
    {
        const int wv = tid >> 6, lane = tid & 63;
        for (int pair = wv; pair < T_TILE * NBANDS; pair += 8) {
            const int t = pair & 7, n = pair >> 3;
            float v = x_s[t][n][lane];
            float sm = v, mx = v, mn = v;
            #pragma unroll
            for (int mk = 32; mk >= 1; mk >>= 1) {
                sm += __shfl_xor(sm, mk);
                mx = fmaxf(mx, __shfl_xor(mx, mk));
                mn = fminf(mn, __shfl_xor(mn, mk));
            }
            if (lane == 0) {
                xbar_s[t][n] = sm * (1.f / 64.f);
                xmax_s[t][n] = mx;
                xmin_s[t][n] = mn;
            }
        }
    }
    __syncthreads();

    // embeddings_mean for 8 t's (all 512 threads, one (t,d) each)
    {
        const int t = tid >> 6, d = tid & 63;
        float cnt = 0.f, accm = 0.f;
        #pragma unroll
        for (int n = 0; n < NBANDS; ++n) {
            cnt += mask_s[t][n];
            accm += mask_s[t][n] * fmaf(xbar_s[t][n], We[n * 64 + d], be[n * 64 + d]);
        }
        out[PFUNC_ELEMS + (size_t)(bt0 + t) * 64 + d] = accm / fmaxf(cnt, 1.f);
    }

    for (int t = 0; t < T_TILE; ++t) {
        // burst all LDS reads for this t: 10x ds_read_b128 + 5 scalars in flight
        float4 xv0[NBANDS], xv1[NBANDS];
        float gi[NBANDS];
        #pragma unroll
        for (int n = 0; n < NBANDS; ++n) {
            xv0[n] = *(const float4*)(&x_s[t][n][jA]);
            xv1[n] = *(const float4*)(&x_s[t][n][jB]);
            gi[n]  = x_s[t][n][i];
        }

        float acc[8];
        #pragma unroll
        for (int jj = 0; jj < 8; ++jj) acc[jj] = 0.f;

        #pragma unroll
        for (int n = 0; n < NBANDS; ++n) {
            // base-2 logits coefficient (0.25*log2e folded into acw/bcw)
            const float g2 = fmaf(acw_s[n], gi[n], bcw_s[n]);
            // branchless conservative row bound over ALL j (unmasked exp2 safe)
            const float negm = -fmaxf(g2 * xmax_s[t][n], g2 * xmin_s[t][n]);
            float e0 = __builtin_amdgcn_exp2f(fmaf(g2, xv0[n].x, negm));
            float e1 = __builtin_amdgcn_exp2f(fmaf(g2, xv0[n].y, negm));
            float e2 = __builtin_amdgcn_exp2f(fmaf(g2, xv0[n].z, negm));
            float e3 = __builtin_amdgcn_exp2f(fmaf(g2, xv0[n].w, negm));
            float e4 = __builtin_amdgcn_exp2f(fmaf(g2, xv1[n].x, negm));
            float e5 = __builtin_amdgcn_exp2f(fmaf(g2, xv1[n].y, negm));
            float e6 = __builtin_amdgcn_exp2f(fmaf(g2, xv1[n].z, negm));
            float e7 = __builtin_amdgcn_exp2f(fmaf(g2, xv1[n].w, negm));
            // masked Z via two fma chains; the 8-lane group jointly covers all
            // 64 cols, so the DPP reduce still yields the full row sum.
            float z0 = e0 * a0.x;
            z0 = fmaf(e1, a0.y, z0);
            z0 = fmaf(e2, a0.z, z0);
            z0 = fmaf(e3, a0.w, z0);
            float z1 = e4 * a1.x;
            z1 = fmaf(e5, a1.y, z1);
            z1 = fmaf(e6, a1.z, z1);
            z1 = fmaf(e7, a1.w, z1);
            float Z = z0 + z1;
            Z = DPP_ADD(Z, 0xB1);    // + lane^1
            Z = DPP_ADD(Z, 0x4E);    // + lane^2
            Z = DPP_ADD(Z, 0x141);   // + mirrored quad (8-lane group total)
            const float sc = w_s[t][n] * __builtin_amdgcn_rcpf(fmaxf(Z, 1e-30f));
            // unmasked accumulate; mask applied once at the store
            acc[0] = fmaf(e0, sc, acc[0]);
            acc[1] = fmaf(e1, sc, acc[1]);
            acc[2] = fmaf(e2, sc, acc[2]);
            acc[3] = fmaf(e3, sc, acc[3]);
            acc[4] = fmaf(e4, sc, acc[4]);
            acc[5] = fmaf(e5, sc, acc[5]);
            acc[6] = fmaf(e6, sc, acc[6]);
            acc[7] = fmaf(e7, sc, acc[7]);
        }

        // apply adjacency mask once; nt stores form FULL 64 B lines
        float* rowp = out + ((size_t)(bt0 + t) * 64 + i) * 64;
        f32x4 o0 = {acc[0] * a0.x, acc[1] * a0.y, acc[2] * a0.z, acc[3] * a0.w};
        f32x4 o1 = {acc[4] * a1.x, acc[5] * a1.y, acc[6] * a1.z, acc[7] * a1.w};
        __builtin_nontemporal_store(o0, (f32x4*)(rowp + jA));
        __builtin_nontemporal_store(o1, (f32x4*)(rowp + jB));
    }
}

extern "C" void kernel_launch(void* const* d_in, const int* in_sizes, int n_in,
                              void* d_out, int out_size, void* d_ws, size_t ws_size,
                              hipStream_t stream) {
    const float* x     = (const float*)d_in[0];
    const float* adj   = (const float*)d_in[1];
    const float* amask = (const float*)d_in[2];
    const float* alpha = (const float*)d_in[3];
    const float* We    = (const float*)d_in[4];
    const float* be    = (const float*)d_in[5];
    const float* Wq    = (const float*)d_in[6];
    const float* Wk    = (const float*)d_in[7];
    float* out = (float*)d_out;

    bfp_kernel<<<512, 512, 0, stream>>>(x, adj, amask, alpha, We, be, Wq, Wk, out);
}